// Round 11
// baseline (188.238 us; speedup 1.0000x reference)
//
#include <hip/hip_runtime.h>
#include <cstdint>
#include <cstddef>

#define D 256
#define HEADS 8
#define HD 32
#define NB 2
#define LQ 12240
#define NQ (NB * LQ)        // 24480
#define PLANE (LQ * HD)     // 391680 elements per (n,h) plane

typedef __attribute__((ext_vector_type(8))) short bf16x8;
typedef __attribute__((ext_vector_type(4))) float f32x4;
typedef __bf16 bf16x2 __attribute__((ext_vector_type(2)));

__device__ __forceinline__ ushort f2bf(float f) {
    union { float f; uint32_t u; } c; c.f = f;
    uint32_t u = c.u;
    uint32_t r = (u + 0x7fffu + ((u >> 16) & 1u)) >> 16;   // RNE, finite inputs
    return (ushort)r;
}
__device__ __forceinline__ float bflo(uint32_t u) { return __uint_as_float(u << 16); }
__device__ __forceinline__ float bfhi(uint32_t u) { return __uint_as_float(u & 0xffff0000u); }

// f32 <-> f16 (RNE via hardware cvt)
__device__ __forceinline__ ushort f2h(float f) {
    _Float16 h = (_Float16)f;
    return __builtin_bit_cast(ushort, h);
}
__device__ __forceinline__ float h2f(ushort u) {
    return (float)__builtin_bit_cast(_Float16, u);
}

// c += a_pair . b_pair  (bf16 pairs packed in u32, f32 accumulate)
__device__ __forceinline__ float dot2bf(uint32_t a, uint32_t b, float c) {
#if __has_builtin(__builtin_amdgcn_fdot2_f32_bf16)
    return __builtin_amdgcn_fdot2_f32_bf16(__builtin_bit_cast(bf16x2, a),
                                           __builtin_bit_cast(bf16x2, b), c, false);
#else
    return c + bflo(a) * bflo(b) + bfhi(a) * bfhi(b);
#endif
}

// ---------------------------------------------------------------------------
// K0: weight/bias conversion + src fp32->bf16 (merged; branches block-uniform).
// ---------------------------------------------------------------------------
__global__ __launch_bounds__(256) void conv_kernel(
    const float* __restrict__ w_value, const float* __restrict__ w_off,
    const float* __restrict__ w_attn,  const float* __restrict__ b_value,
    const float* __restrict__ b_off,   const float* __restrict__ b_attn,
    const float* __restrict__ w_out,   const float* __restrict__ src,
    ushort* __restrict__ B_pack, ushort* __restrict__ w_out_t,
    float* __restrict__ b_pack, ushort* __restrict__ src_bf)
{
    const int b = blockIdx.x, k = threadIdx.x;
    if (b >= 899) {
        const size_t i = ((size_t)(b - 899) * 256 + k) * 4;
        float4 v = *(const float4*)(src + i);
        ushort4 o;
        o.x = f2bf(v.x); o.y = f2bf(v.y); o.z = f2bf(v.z); o.w = f2bf(v.w);
        *(ushort4*)(src_bf + i) = o;
        return;
    }
    if (b < 640) {
        float v;
        if (b < 256)      v = w_value[(size_t)k * 256 + b];
        else if (b < 512) v = w_off[(size_t)k * 256 + (b - 256)];
        else              v = w_attn[(size_t)k * 128 + (b - 512)];
        B_pack[(size_t)b * 256 + k] = f2bf(v);
    } else if (b < 896) {
        int n = b - 640;
        w_out_t[(size_t)n * 256 + k] = f2bf(w_out[(size_t)k * 256 + n]);
    } else if (b == 896) {
        b_pack[k] = b_value[k];
    } else if (b == 897) {
        b_pack[256 + k] = b_off[k];
    } else {
        if (k < 128) b_pack[512 + k] = b_attn[k];
    }
}

// ---------------------------------------------------------------------------
// K1 (v6): fused projections via MFMA, TWO B panels staged in LDS
// (unchanged from round 10, passing).
// ---------------------------------------------------------------------------
__global__ __launch_bounds__(256, 2) void proj_gemm(
    const ushort* __restrict__ src_bf, const ushort* __restrict__ B_pack,
    const float* __restrict__ b_pack,
    ushort* __restrict__ val_t, ushort* __restrict__ off_f16,
    ushort* __restrict__ attn_f16)
{
    __shared__ ushort blds[128 * 264];  // 67,584 B
    const int tid = threadIdx.x;
    const int wv = tid >> 6, lane = tid & 63;
    const int quad = lane >> 4, ln = lane & 15;
    const int mc = blockIdx.x;          // 0..191
    const int py = blockIdx.y;          // 0..4

    // stage B panels: 128 rows x 32 uint4, row stride 264 shorts in LDS
#pragma unroll
    for (int j = 0; j < 16; ++j) {
        const int idx = j * 256 + tid;
        const int row = idx >> 5, c16 = idx & 31;
        *(uint4*)(blds + row * 264 + c16 * 8) =
            *(const uint4*)(B_pack + (size_t)(py * 128 + row) * 256 + c16 * 8);
    }

    float bias[8];
#pragma unroll
    for (int u = 0; u < 8; ++u) bias[u] = b_pack[py * 128 + u * 16 + ln];

    const int rowbase = mc * 128 + wv * 32;
    bool va[2];
#pragma unroll
    for (int rt = 0; rt < 2; ++rt) va[rt] = (rowbase + rt * 16 + ln) < NQ;

    __syncthreads();

    f32x4 acc[2][8];
#pragma unroll
    for (int rt = 0; rt < 2; ++rt)
#pragma unroll
        for (int u = 0; u < 8; ++u) acc[rt][u] = (f32x4){0.f, 0.f, 0.f, 0.f};

#pragma unroll 2
    for (int kc = 0; kc < 8; ++kc) {
        bf16x8 af[2], bf[8];
#pragma unroll
        for (int rt = 0; rt < 2; ++rt) {
            bf16x8 v = {0, 0, 0, 0, 0, 0, 0, 0};
            if (va[rt])
                v = *(const bf16x8*)(src_bf +
                      (size_t)(rowbase + rt * 16 + ln) * 256 + kc * 32 + quad * 8);
            af[rt] = v;
        }
#pragma unroll
        for (int u = 0; u < 8; ++u)
            bf[u] = *(const bf16x8*)(blds + (u * 16 + ln) * 264 + kc * 32 + quad * 8);
#pragma unroll
        for (int rt = 0; rt < 2; ++rt)
#pragma unroll
            for (int u = 0; u < 8; ++u)
                acc[rt][u] = __builtin_amdgcn_mfma_f32_16x16x32_bf16(
                                 af[rt], bf[u], acc[rt][u], 0, 0, 0);
    }

    if (py < 2) {
#pragma unroll
        for (int u = 0; u < 8; ++u) {
            const int n_g = py * 128 + u * 16 + ln;
            const int h = n_g >> 5, hd = n_g & 31;
#pragma unroll
            for (int rt = 0; rt < 2; ++rt)
#pragma unroll
                for (int reg = 0; reg < 4; ++reg) {
                    const int row = rowbase + rt * 16 + quad * 4 + reg;
                    if (row < NQ) {
                        const int nb = row >= LQ; const int ql = row - nb * LQ;
                        val_t[(((size_t)(nb * 8 + h)) * LQ + ql) * 32 + hd] =
                            f2bf(acc[rt][u][reg] + bias[u]);
                    }
                }
        }
    } else if (py < 4) {
#pragma unroll
        for (int u = 0; u < 8; ++u) {
            const int col = (py - 2) * 128 + u * 16 + ln;
#pragma unroll
            for (int rt = 0; rt < 2; ++rt)
#pragma unroll
                for (int reg = 0; reg < 4; ++reg) {
                    const int row = rowbase + rt * 16 + quad * 4 + reg;
                    if (row < NQ)
                        off_f16[(size_t)row * 256 + col] =
                            f2h(acc[rt][u][reg] + bias[u]);
                }
        }
    } else {
#pragma unroll
        for (int u = 0; u < 8; ++u) {
            const int col = u * 16 + ln;
#pragma unroll
            for (int rt = 0; rt < 2; ++rt)
#pragma unroll
                for (int reg = 0; reg < 4; ++reg) {
                    const int row = rowbase + rt * 16 + quad * 4 + reg;
                    if (row < NQ)
                        attn_f16[(size_t)row * 128 + col] =
                            f2h(acc[rt][u][reg] + bias[u]);
                }
        }
    }
}

// ---------------------------------------------------------------------------
// K2 (v5): softmax + sampling + bilinear gather DIRECTLY from val_t.
// pair_kernel is GONE: each point gathers two uint2 (4 channels at pos, 4 at
// nxt = pos or pos+32 shorts) and packs (v[pos][c], v[nxt][c]) u32 pairs
// in-register (4 ALU/point) -- bit-identical to the old val_pair entries.
// Same L2 bytes per gather; table footprint halves (783 KB/plane).
// sm_i2 holds the nxt offset (same x-increment for both y rows).
// ---------------------------------------------------------------------------
__global__ __launch_bounds__(256) void sample_kernel(
    const float* __restrict__ ref_pts,
    const ushort* __restrict__ val_t,
    const ushort* __restrict__ off_f16,
    const ushort* __restrict__ attn_f16,
    uint32_t* __restrict__ sampled)
{
    __shared__ uint32_t sm_i[16][2][18];
    __shared__ uint32_t sm_i2[16][2][18];
    __shared__ uint32_t sm_w[16][2][18];
    const int gl = threadIdx.x >> 4;
    const int ln = threadIdx.x & 15;
    const int h     = blockIdx.x & 7;        // -> XCD id (heuristic)
    const int chunk = blockIdx.x >> 3;       // 0..1529
    const int qg = chunk * 16 + gl;
    const int n  = (qg >= LQ) ? 1 : 0;
    const int l  = ln >> 2;

    // softmax over 16 (level,point) logits of this head
    float a = h2f(attn_f16[(size_t)qg * 128 + h * 16 + ln]);
    float m = a;
#pragma unroll
    for (int s = 8; s; s >>= 1) m = fmaxf(m, __shfl_xor(m, s, 16));
    float e = __expf(a - m);
    float ssum = e;
#pragma unroll
    for (int s = 8; s; s >>= 1) ssum += __shfl_xor(ssum, s, 16);
    float aw = e * __builtin_amdgcn_rcpf(ssum);

    uint32_t oxy = *(const uint32_t*)(off_f16 + (size_t)qg * 256 + h * 32 + ln * 2);
    float ox = h2f((ushort)(oxy & 0xffffu));
    float oy = h2f((ushort)(oxy >> 16));
    float rx = ref_pts[(qg * 4 + l) * 2 + 0];
    float ry = ref_pts[(qg * 4 + l) * 2 + 1];

    const int Wi = 96 >> l;
    const int Hi = Wi;
    const int s0 = (l > 0 ? 9216 : 0) + (l > 1 ? 2304 : 0) + (l > 2 ? 576 : 0);
    const float Wf = (float)Wi, Hf = (float)Hi;

    float x = fmaf(rx, Wf, ox) - 0.5f;       // == (rx + ox/Wf)*Wf - 0.5
    float y = fmaf(ry, Hf, oy) - 0.5f;
    float x0f = floorf(x), y0f = floorf(y);
    float lx = x - x0f, ly = y - y0f;
    int x0 = (int)x0f, y0 = (int)y0f;

    float wy0 = (y0 >= 0 && y0 < Hi) ? (1.f - ly) : 0.f;
    float wy1 = (y0 + 1 >= 0 && y0 + 1 < Hi) ? ly : 0.f;
    int yc0 = min(max(y0, 0), Hi - 1);
    int yc1 = min(max(y0 + 1, 0), Hi - 1);
    float wl = (x0 >= 0 && x0 < Wi) ? (1.f - lx) : 0.f;
    float wh = (x0 + 1 >= 0 && x0 + 1 < Wi) ? lx : 0.f;
    float pl, ph;
    int xe;
    if (x0 < 0) { pl = wh; ph = 0.f; xe = x0 + 1; }
    else        { pl = wl; ph = wh;  xe = x0; }
    int xc = min(max(xe, 0), Wi - 1);
    pl *= aw; ph *= aw;

    const uint32_t inc = (xc >= Wi - 1) ? 0u : 32u;   // ph==0 when neighbor OOB
    const uint32_t o0 = (uint32_t)(s0 + yc0 * Wi + xc) * 32u;
    const uint32_t o1 = (uint32_t)(s0 + yc1 * Wi + xc) * 32u;
    sm_i [gl][0][ln] = o0;
    sm_i [gl][1][ln] = o1;
    sm_i2[gl][0][ln] = o0 + inc;
    sm_i2[gl][1][ln] = o1 + inc;
    sm_w [gl][0][ln] = ((uint32_t)f2bf(ph * wy0) << 16) | (uint32_t)f2bf(pl * wy0);
    sm_w [gl][1][ln] = ((uint32_t)f2bf(ph * wy1) << 16) | (uint32_t)f2bf(pl * wy1);
    // intra-wave LDS write->read: same-wave DS ops execute in order

    const int half = ln >> 3;              // 0: row0, 1: row1
    const int cb2  = (ln & 7) * 4;         // ushort channel base (4 channels)
    const ushort* vt = val_t + (size_t)(n * HEADS + h) * PLANE + cb2;

    float a0 = 0.f, a1 = 0.f, a2 = 0.f, a3 = 0.f;
#pragma unroll
    for (int c = 0; c < 2; ++c) {
        uint2    lo[8], hi[8];
        uint32_t wpk[8];
#pragma unroll
        for (int p = 0; p < 8; ++p) {
            lo[p]  = *(const uint2*)(vt + sm_i [gl][half][c * 8 + p]);
            hi[p]  = *(const uint2*)(vt + sm_i2[gl][half][c * 8 + p]);
            wpk[p] = sm_w[gl][half][c * 8 + p];
        }
#pragma unroll
        for (int p = 0; p < 8; ++p) {
            uint32_t p0 = (lo[p].x & 0x0000ffffu) | (hi[p].x << 16);
            uint32_t p1 = (lo[p].x >> 16)         | (hi[p].x & 0xffff0000u);
            uint32_t p2 = (lo[p].y & 0x0000ffffu) | (hi[p].y << 16);
            uint32_t p3 = (lo[p].y >> 16)         | (hi[p].y & 0xffff0000u);
            a0 = dot2bf(p0, wpk[p], a0);
            a1 = dot2bf(p1, wpk[p], a1);
            a2 = dot2bf(p2, wpk[p], a2);
            a3 = dot2bf(p3, wpk[p], a3);
        }
    }
    // combine row0 + row1 partials (lanes ln and ln^8 hold the same channels)
    a0 += __shfl_xor(a0, 8, 16);
    a1 += __shfl_xor(a1, 8, 16);
    a2 += __shfl_xor(a2, 8, 16);
    a3 += __shfl_xor(a3, 8, 16);
    if (ln < 8) {
        uint2 rr;
        rr.x = ((uint32_t)f2bf(a1) << 16) | (uint32_t)f2bf(a0);
        rr.y = ((uint32_t)f2bf(a3) << 16) | (uint32_t)f2bf(a2);
        *(uint2*)(sampled + (size_t)qg * 128 + h * 16 + 2 * ln) = rr;
    }
}

// ---------------------------------------------------------------------------
// K3 (v5): fused out-projection + residual + LayerNorm, FULL B staged in
// LDS exactly once (unchanged from round 9/10, passing).
// ---------------------------------------------------------------------------
__global__ __launch_bounds__(256, 1) void out_ln_gemm(
    const ushort* __restrict__ sampled, const ushort* __restrict__ w_out_t,
    const float* __restrict__ b_out,    const float* __restrict__ src,
    const float* __restrict__ gamma,    const float* __restrict__ beta,
    float* __restrict__ out)
{
    __shared__ ushort blds[256 * 264];  // 135,168 B, write-once
    __shared__ float sm[2][4][16][2];   // [parity][wave][row16][{s1,s2}]
    const int tid = threadIdx.x;
    const int wv = tid >> 6, lane = tid & 63;
    const int quad = lane >> 4, ln = lane & 15;

    // stage full B^T [col][K] once: 8192 uint4, 32 per thread
#pragma unroll 4
    for (int j = 0; j < 32; ++j) {
        const int idx = j * 256 + tid;
        const int col = idx >> 5, c16 = idx & 31;
        *(uint4*)(blds + col * 264 + c16 * 8) =
            *(const uint4*)(w_out_t + (size_t)col * 256 + c16 * 8);
    }

    float bias[4], gam[4], bet[4];
#pragma unroll
    for (int t = 0; t < 4; ++t) {
        const int col = wv * 64 + t * 16 + ln;
        bias[t] = b_out[col];
        gam[t]  = gamma[col];
        bet[t]  = beta[col];
    }

    int base = blockIdx.x * 96;         // grid 255: rows [base, base+96)

    // A fragments for iter 0 (global loads overlap the staging drain)
    bf16x8 af[8];
    {
        const ushort* ap = sampled + (size_t)(base + ln) * 256 + quad * 8;
#pragma unroll
        for (int s = 0; s < 8; ++s) af[s] = *(const bf16x8*)(ap + s * 32);
    }

    __syncthreads();                    // staging complete; blds read-only below

    for (int i = 0; i < 6; ++i) {
        // next-iter A fragments (latency hides under MFMA + epilogue)
        bf16x8 afn[8];
        if (i < 5) {
            const ushort* apn = sampled + (size_t)(base + 16 + ln) * 256 + quad * 8;
#pragma unroll
            for (int s = 0; s < 8; ++s) afn[s] = *(const bf16x8*)(apn + s * 32);
        }
        // this-iter residual src values
        float sv[4][4];
#pragma unroll
        for (int reg = 0; reg < 4; ++reg) {
            const float* sp = src + (size_t)(base + quad * 4 + reg) * 256 + wv * 64 + ln;
#pragma unroll
            for (int t = 0; t < 4; ++t) sv[reg][t] = sp[t * 16];
        }

        f32x4 acc[4] = {{0,0,0,0},{0,0,0,0},{0,0,0,0},{0,0,0,0}};
#pragma unroll
        for (int s = 0; s < 8; ++s)
#pragma unroll
            for (int t = 0; t < 4; ++t) {
                bf16x8 bf = *(const bf16x8*)(blds +
                              (size_t)(wv * 64 + t * 16 + ln) * 264 + s * 32 + quad * 8);
                acc[t] = __builtin_amdgcn_mfma_f32_16x16x32_bf16(af[s], bf, acc[t], 0, 0, 0);
            }

        // bias + residual + per-row partial sums (row = base + quad*4 + reg)
#pragma unroll
        for (int reg = 0; reg < 4; ++reg) {
            float s1 = 0.f, s2 = 0.f;
#pragma unroll
            for (int t = 0; t < 4; ++t) {
                float v = acc[t][reg] + bias[t] + sv[reg][t];
                acc[t][reg] = v;
                s1 += v; s2 += v * v;
            }
#pragma unroll
            for (int o = 8; o; o >>= 1) {
                s1 += __shfl_xor(s1, o, 16);
                s2 += __shfl_xor(s2, o, 16);
            }
            if (ln == 0) {
                sm[i & 1][wv][quad * 4 + reg][0] = s1;
                sm[i & 1][wv][quad * 4 + reg][1] = s2;
            }
        }
        __syncthreads();

#pragma unroll
        for (int reg = 0; reg < 4; ++reg) {
            const int r16 = quad * 4 + reg;
            float s1 = sm[i & 1][0][r16][0] + sm[i & 1][1][r16][0]
                     + sm[i & 1][2][r16][0] + sm[i & 1][3][r16][0];
            float s2 = sm[i & 1][0][r16][1] + sm[i & 1][1][r16][1]
                     + sm[i & 1][2][r16][1] + sm[i & 1][3][r16][1];
            float mu  = s1 * (1.f / 256.f);
            float var = s2 * (1.f / 256.f) - mu * mu;
            float rs  = rsqrtf(var + 1e-5f);
            const int row = base + quad * 4 + reg;
            float* op = out + (size_t)row * 256 + wv * 64 + ln;
#pragma unroll
            for (int t = 0; t < 4; ++t)
                op[t * 16] = (acc[t][reg] - mu) * rs * gam[t] + bet[t];
        }

        base += 16;
#pragma unroll
        for (int s = 0; s < 8; ++s) af[s] = afn[s];
    }
}

// ---------------------------------------------------------------------------
extern "C" void kernel_launch(void* const* d_in, const int* in_sizes, int n_in,
                              void* d_out, int out_size, void* d_ws, size_t ws_size,
                              hipStream_t stream)
{
    const float* src     = (const float*)d_in[0];
    const float* refp    = (const float*)d_in[1];
    const float* w_value = (const float*)d_in[4];
    const float* b_value = (const float*)d_in[5];
    const float* w_off   = (const float*)d_in[6];
    const float* b_off   = (const float*)d_in[7];
    const float* w_attn  = (const float*)d_in[8];
    const float* b_attn  = (const float*)d_in[9];
    const float* w_out   = (const float*)d_in[10];
    const float* b_out   = (const float*)d_in[11];
    const float* gamma   = (const float*)d_in[12];
    const float* beta    = (const float*)d_in[13];

    char* ws = (char*)d_ws;
    ushort*   val_t    = (ushort*)  (ws);                   // 12,533,760 B
    ushort*   src_bf   = (ushort*)  (ws + 12533760);        // 12,533,760 B (no alias)
    ushort*   off_f16  = (ushort*)  (ws + 37601280);        // 12,533,760 B
    ushort*   attn_f16 = (ushort*)  (ws + 50135040);        //  6,266,880 B
    uint32_t* sampled  = (uint32_t*)(ws + 62668800);        // 12,533,760 B (no alias)
    ushort*   B_pack   = (ushort*)  (ws + 75202560);        //    327,680 B
    ushort*   w_out_t  = (ushort*)  (ws + 75530240);        //    131,072 B
    float*    b_pack   = (float*)   (ws + 75661312);        //      2,560 B
    float*    out      = (float*)d_out;

    conv_kernel<<<7019, 256, 0, stream>>>(w_value, w_off, w_attn, b_value, b_off,
                                          b_attn, w_out, src, B_pack, w_out_t,
                                          b_pack, src_bf);
    proj_gemm<<<dim3(192, 5), 256, 0, stream>>>(src_bf, B_pack, b_pack, val_t,
                                                off_f16, attn_f16);
    sample_kernel<<<12240, 256, 0, stream>>>(refp, val_t, off_f16, attn_f16,
                                             sampled);
    out_ln_gemm<<<255, 256, 0, stream>>>((const ushort*)sampled, w_out_t,
                                         b_out, src, gamma, beta, out);
}

// Round 13
// 179.090 us; speedup vs baseline: 1.0511x; 1.0511x over previous
//
#include <hip/hip_runtime.h>
#include <cstdint>
#include <cstddef>

#define D 256
#define HEADS 8
#define HD 32
#define NB 2
#define LQ 12240
#define NQ (NB * LQ)        // 24480
#define PLANE (LQ * HD)     // 391680 elements per (n,h) plane

typedef __attribute__((ext_vector_type(8))) short bf16x8;
typedef __attribute__((ext_vector_type(4))) float f32x4;
typedef __bf16 bf16x2 __attribute__((ext_vector_type(2)));

__device__ __forceinline__ ushort f2bf(float f) {
    union { float f; uint32_t u; } c; c.f = f;
    uint32_t u = c.u;
    uint32_t r = (u + 0x7fffu + ((u >> 16) & 1u)) >> 16;   // RNE, finite inputs
    return (ushort)r;
}
__device__ __forceinline__ float bflo(uint32_t u) { return __uint_as_float(u << 16); }
__device__ __forceinline__ float bfhi(uint32_t u) { return __uint_as_float(u & 0xffff0000u); }

// f32 <-> f16 (RNE via hardware cvt)
__device__ __forceinline__ ushort f2h(float f) {
    _Float16 h = (_Float16)f;
    return __builtin_bit_cast(ushort, h);
}
__device__ __forceinline__ float h2f(ushort u) {
    return (float)__builtin_bit_cast(_Float16, u);
}

// c += a_pair . b_pair  (bf16 pairs packed in u32, f32 accumulate)
__device__ __forceinline__ float dot2bf(uint32_t a, uint32_t b, float c) {
#if __has_builtin(__builtin_amdgcn_fdot2_f32_bf16)
    return __builtin_amdgcn_fdot2_f32_bf16(__builtin_bit_cast(bf16x2, a),
                                           __builtin_bit_cast(bf16x2, b), c, false);
#else
    return c + bflo(a) * bflo(b) + bfhi(a) * bfhi(b);
#endif
}

// ---------------------------------------------------------------------------
// K0: weight/bias conversion + src fp32->bf16 (merged; branches block-uniform).
// ---------------------------------------------------------------------------
__global__ __launch_bounds__(256) void conv_kernel(
    const float* __restrict__ w_value, const float* __restrict__ w_off,
    const float* __restrict__ w_attn,  const float* __restrict__ b_value,
    const float* __restrict__ b_off,   const float* __restrict__ b_attn,
    const float* __restrict__ w_out,   const float* __restrict__ src,
    ushort* __restrict__ B_pack, ushort* __restrict__ w_out_t,
    float* __restrict__ b_pack, ushort* __restrict__ src_bf)
{
    const int b = blockIdx.x, k = threadIdx.x;
    if (b >= 899) {
        const size_t i = ((size_t)(b - 899) * 256 + k) * 4;
        float4 v = *(const float4*)(src + i);
        ushort4 o;
        o.x = f2bf(v.x); o.y = f2bf(v.y); o.z = f2bf(v.z); o.w = f2bf(v.w);
        *(ushort4*)(src_bf + i) = o;
        return;
    }
    if (b < 640) {
        float v;
        if (b < 256)      v = w_value[(size_t)k * 256 + b];
        else if (b < 512) v = w_off[(size_t)k * 256 + (b - 256)];
        else              v = w_attn[(size_t)k * 128 + (b - 512)];
        B_pack[(size_t)b * 256 + k] = f2bf(v);
    } else if (b < 896) {
        int n = b - 640;
        w_out_t[(size_t)n * 256 + k] = f2bf(w_out[(size_t)k * 256 + n]);
    } else if (b == 896) {
        b_pack[k] = b_value[k];
    } else if (b == 897) {
        b_pack[256 + k] = b_off[k];
    } else {
        if (k < 128) b_pack[512 + k] = b_attn[k];
    }
}

// ---------------------------------------------------------------------------
// K1 (v6): fused projections via MFMA, TWO B panels staged in LDS
// (proven 180.1 us build).
// ---------------------------------------------------------------------------
__global__ __launch_bounds__(256, 2) void proj_gemm(
    const ushort* __restrict__ src_bf, const ushort* __restrict__ B_pack,
    const float* __restrict__ b_pack,
    ushort* __restrict__ val_t, ushort* __restrict__ off_f16,
    ushort* __restrict__ attn_f16)
{
    __shared__ ushort blds[128 * 264];  // 67,584 B
    const int tid = threadIdx.x;
    const int wv = tid >> 6, lane = tid & 63;
    const int quad = lane >> 4, ln = lane & 15;
    const int mc = blockIdx.x;          // 0..191
    const int py = blockIdx.y;          // 0..4

    // stage B panels: 128 rows x 32 uint4, row stride 264 shorts in LDS
#pragma unroll
    for (int j = 0; j < 16; ++j) {
        const int idx = j * 256 + tid;
        const int row = idx >> 5, c16 = idx & 31;
        *(uint4*)(blds + row * 264 + c16 * 8) =
            *(const uint4*)(B_pack + (size_t)(py * 128 + row) * 256 + c16 * 8);
    }

    float bias[8];
#pragma unroll
    for (int u = 0; u < 8; ++u) bias[u] = b_pack[py * 128 + u * 16 + ln];

    const int rowbase = mc * 128 + wv * 32;
    bool va[2];
#pragma unroll
    for (int rt = 0; rt < 2; ++rt) va[rt] = (rowbase + rt * 16 + ln) < NQ;

    __syncthreads();

    f32x4 acc[2][8];
#pragma unroll
    for (int rt = 0; rt < 2; ++rt)
#pragma unroll
        for (int u = 0; u < 8; ++u) acc[rt][u] = (f32x4){0.f, 0.f, 0.f, 0.f};

#pragma unroll 2
    for (int kc = 0; kc < 8; ++kc) {
        bf16x8 af[2], bf[8];
#pragma unroll
        for (int rt = 0; rt < 2; ++rt) {
            bf16x8 v = {0, 0, 0, 0, 0, 0, 0, 0};
            if (va[rt])
                v = *(const bf16x8*)(src_bf +
                      (size_t)(rowbase + rt * 16 + ln) * 256 + kc * 32 + quad * 8);
            af[rt] = v;
        }
#pragma unroll
        for (int u = 0; u < 8; ++u)
            bf[u] = *(const bf16x8*)(blds + (u * 16 + ln) * 264 + kc * 32 + quad * 8);
#pragma unroll
        for (int rt = 0; rt < 2; ++rt)
#pragma unroll
            for (int u = 0; u < 8; ++u)
                acc[rt][u] = __builtin_amdgcn_mfma_f32_16x16x32_bf16(
                                 af[rt], bf[u], acc[rt][u], 0, 0, 0);
    }

    if (py < 2) {
#pragma unroll
        for (int u = 0; u < 8; ++u) {
            const int n_g = py * 128 + u * 16 + ln;
            const int h = n_g >> 5, hd = n_g & 31;
#pragma unroll
            for (int rt = 0; rt < 2; ++rt)
#pragma unroll
                for (int reg = 0; reg < 4; ++reg) {
                    const int row = rowbase + rt * 16 + quad * 4 + reg;
                    if (row < NQ) {
                        const int nb = row >= LQ; const int ql = row - nb * LQ;
                        val_t[(((size_t)(nb * 8 + h)) * LQ + ql) * 32 + hd] =
                            f2bf(acc[rt][u][reg] + bias[u]);
                    }
                }
        }
    } else if (py < 4) {
#pragma unroll
        for (int u = 0; u < 8; ++u) {
            const int col = (py - 2) * 128 + u * 16 + ln;
#pragma unroll
            for (int rt = 0; rt < 2; ++rt)
#pragma unroll
                for (int reg = 0; reg < 4; ++reg) {
                    const int row = rowbase + rt * 16 + quad * 4 + reg;
                    if (row < NQ)
                        off_f16[(size_t)row * 256 + col] =
                            f2h(acc[rt][u][reg] + bias[u]);
                }
        }
    } else {
#pragma unroll
        for (int u = 0; u < 8; ++u) {
            const int col = u * 16 + ln;
#pragma unroll
            for (int rt = 0; rt < 2; ++rt)
#pragma unroll
                for (int reg = 0; reg < 4; ++reg) {
                    const int row = rowbase + rt * 16 + quad * 4 + reg;
                    if (row < NQ)
                        attn_f16[(size_t)row * 128 + col] =
                            f2h(acc[rt][u][reg] + bias[u]);
                }
        }
    }
}

// ---------------------------------------------------------------------------
// K1b (v2): build x-pair table -- 4 channels per thread (round-11 proved
// sample is VALU/issue-bound, so pre-interleaving pairs off the critical
// kernel is worth its 37.5 MB of HBM traffic).
// ---------------------------------------------------------------------------
__global__ __launch_bounds__(256) void pair_kernel(
    const ushort* __restrict__ val_t, uint32_t* __restrict__ val_pair)
{
    const uint32_t j = blockIdx.x * 256 + threadIdx.x;   // < 1,566,720
    const uint32_t c4 = (j & 7u) * 4u;                   // channel base 0..28
    const uint32_t rest = j >> 3;                        // plane*LQ + pos
    const uint32_t plane = rest / LQ;
    const uint32_t pos = rest - plane * LQ;
    int l = (pos >= 9216) + (pos >= 11520) + (pos >= 12096);
    uint32_t s0 = (l > 0 ? 9216u : 0u) + (l > 1 ? 2304u : 0u) + (l > 2 ? 576u : 0u);
    uint32_t Wi = 96u >> l;
    uint32_t p = pos - s0;
    uint32_t q = (p / 3u) >> (5 - l);          // p / Wi  (Wi = 3<<(5-l))
    uint32_t xr = p - q * Wi;                  // p % Wi
    uint32_t nxt = (xr == Wi - 1u) ? pos : pos + 1u;
    const ushort* base = val_t + (size_t)plane * PLANE;
    uint2 lo = *(const uint2*)(base + pos * 32 + c4);
    uint2 hi = *(const uint2*)(base + nxt * 32 + c4);
    uint4 o;
    o.x = (lo.x & 0x0000ffffu) | (hi.x << 16);
    o.y = (lo.x >> 16)         | (hi.x & 0xffff0000u);
    o.z = (lo.y & 0x0000ffffu) | (hi.y << 16);
    o.w = (lo.y >> 16)         | (hi.y & 0xffff0000u);
    *(uint4*)(val_pair + ((size_t)rest * 32 + c4)) = o;
}

// ---------------------------------------------------------------------------
// K2 (v4): softmax + sampling + bilinear gather from val_pair
// (16 uint4 gathers/lane, no in-register packing).
// ---------------------------------------------------------------------------
__global__ __launch_bounds__(256) void sample_kernel(
    const float* __restrict__ ref_pts,
    const uint32_t* __restrict__ val_pair,
    const ushort* __restrict__ off_f16,
    const ushort* __restrict__ attn_f16,
    uint32_t* __restrict__ sampled)
{
    __shared__ uint32_t sm_i[16][2][18];
    __shared__ uint32_t sm_w[16][2][18];
    const int gl = threadIdx.x >> 4;
    const int ln = threadIdx.x & 15;
    const int h     = blockIdx.x & 7;        // -> XCD id (heuristic)
    const int chunk = blockIdx.x >> 3;       // 0..1529
    const int qg = chunk * 16 + gl;
    const int n  = (qg >= LQ) ? 1 : 0;
    const int l  = ln >> 2;

    // softmax over 16 (level,point) logits of this head
    float a = h2f(attn_f16[(size_t)qg * 128 + h * 16 + ln]);
    float m = a;
#pragma unroll
    for (int s = 8; s; s >>= 1) m = fmaxf(m, __shfl_xor(m, s, 16));
    float e = __expf(a - m);
    float ssum = e;
#pragma unroll
    for (int s = 8; s; s >>= 1) ssum += __shfl_xor(ssum, s, 16);
    float aw = e * __builtin_amdgcn_rcpf(ssum);

    uint32_t oxy = *(const uint32_t*)(off_f16 + (size_t)qg * 256 + h * 32 + ln * 2);
    float ox = h2f((ushort)(oxy & 0xffffu));
    float oy = h2f((ushort)(oxy >> 16));
    float rx = ref_pts[(qg * 4 + l) * 2 + 0];
    float ry = ref_pts[(qg * 4 + l) * 2 + 1];

    const int Wi = 96 >> l;
    const int Hi = Wi;
    const int s0 = (l > 0 ? 9216 : 0) + (l > 1 ? 2304 : 0) + (l > 2 ? 576 : 0);
    const float Wf = (float)Wi, Hf = (float)Hi;

    float x = fmaf(rx, Wf, ox) - 0.5f;       // == (rx + ox/Wf)*Wf - 0.5
    float y = fmaf(ry, Hf, oy) - 0.5f;
    float x0f = floorf(x), y0f = floorf(y);
    float lx = x - x0f, ly = y - y0f;
    int x0 = (int)x0f, y0 = (int)y0f;

    float wy0 = (y0 >= 0 && y0 < Hi) ? (1.f - ly) : 0.f;
    float wy1 = (y0 + 1 >= 0 && y0 + 1 < Hi) ? ly : 0.f;
    int yc0 = min(max(y0, 0), Hi - 1);
    int yc1 = min(max(y0 + 1, 0), Hi - 1);
    float wl = (x0 >= 0 && x0 < Wi) ? (1.f - lx) : 0.f;
    float wh = (x0 + 1 >= 0 && x0 + 1 < Wi) ? lx : 0.f;
    float pl, ph;
    int xe;
    if (x0 < 0) { pl = wh; ph = 0.f; xe = x0 + 1; }
    else        { pl = wl; ph = wh;  xe = x0; }
    int xc = min(max(xe, 0), Wi - 1);
    pl *= aw; ph *= aw;

    sm_i[gl][0][ln] = (uint32_t)(s0 + yc0 * Wi + xc) * 32u;
    sm_i[gl][1][ln] = (uint32_t)(s0 + yc1 * Wi + xc) * 32u;
    sm_w[gl][0][ln] = ((uint32_t)f2bf(ph * wy0) << 16) | (uint32_t)f2bf(pl * wy0);
    sm_w[gl][1][ln] = ((uint32_t)f2bf(ph * wy1) << 16) | (uint32_t)f2bf(pl * wy1);
    // intra-wave LDS write->read: same-wave DS ops execute in order

    const int half = ln >> 3;              // 0: row0, 1: row1
    const int cb   = (ln & 7) * 4;         // u32 channel-pair base
    const uint32_t* plane =
        val_pair + (size_t)(n * HEADS + h) * PLANE + cb;

    float a0 = 0.f, a1 = 0.f, a2 = 0.f, a3 = 0.f;
#pragma unroll
    for (int c = 0; c < 2; ++c) {
        uint4    rv[8];
        uint32_t wpk[8];
#pragma unroll
        for (int p = 0; p < 8; ++p) {
            uint32_t off = sm_i[gl][half][c * 8 + p];
            rv[p]  = *(const uint4*)(plane + off);
            wpk[p] = sm_w[gl][half][c * 8 + p];
        }
#pragma unroll
        for (int p = 0; p < 8; ++p) {
            a0 = dot2bf(rv[p].x, wpk[p], a0);
            a1 = dot2bf(rv[p].y, wpk[p], a1);
            a2 = dot2bf(rv[p].z, wpk[p], a2);
            a3 = dot2bf(rv[p].w, wpk[p], a3);
        }
    }
    // combine row0 + row1 partials (lanes ln and ln^8 hold the same channels)
    a0 += __shfl_xor(a0, 8, 16);
    a1 += __shfl_xor(a1, 8, 16);
    a2 += __shfl_xor(a2, 8, 16);
    a3 += __shfl_xor(a3, 8, 16);
    if (ln < 8) {
        uint2 rr;
        rr.x = ((uint32_t)f2bf(a1) << 16) | (uint32_t)f2bf(a0);
        rr.y = ((uint32_t)f2bf(a3) << 16) | (uint32_t)f2bf(a2);
        *(uint2*)(sampled + (size_t)qg * 128 + h * 16 + 2 * ln) = rr;
    }
}

// ---------------------------------------------------------------------------
// K3 (v5): fused out-projection + residual + LayerNorm, FULL B staged in
// LDS exactly once (unchanged, passing).
// ---------------------------------------------------------------------------
__global__ __launch_bounds__(256, 1) void out_ln_gemm(
    const ushort* __restrict__ sampled, const ushort* __restrict__ w_out_t,
    const float* __restrict__ b_out,    const float* __restrict__ src,
    const float* __restrict__ gamma,    const float* __restrict__ beta,
    float* __restrict__ out)
{
    __shared__ ushort blds[256 * 264];  // 135,168 B, write-once
    __shared__ float sm[2][4][16][2];   // [parity][wave][row16][{s1,s2}]
    const int tid = threadIdx.x;
    const int wv = tid >> 6, lane = tid & 63;
    const int quad = lane >> 4, ln = lane & 15;

    // stage full B^T [col][K] once: 8192 uint4, 32 per thread
#pragma unroll 4
    for (int j = 0; j < 32; ++j) {
        const int idx = j * 256 + tid;
        const int col = idx >> 5, c16 = idx & 31;
        *(uint4*)(blds + col * 264 + c16 * 8) =
            *(const uint4*)(w_out_t + (size_t)col * 256 + c16 * 8);
    }

    float bias[4], gam[4], bet[4];
#pragma unroll
    for (int t = 0; t < 4; ++t) {
        const int col = wv * 64 + t * 16 + ln;
        bias[t] = b_out[col];
        gam[t]  = gamma[col];
        bet[t]  = beta[col];
    }

    int base = blockIdx.x * 96;         // grid 255: rows [base, base+96)

    // A fragments for iter 0 (global loads overlap the staging drain)
    bf16x8 af[8];
    {
        const ushort* ap = sampled + (size_t)(base + ln) * 256 + quad * 8;
#pragma unroll
        for (int s = 0; s < 8; ++s) af[s] = *(const bf16x8*)(ap + s * 32);
    }

    __syncthreads();                    // staging complete; blds read-only below

    for (int i = 0; i < 6; ++i) {
        // next-iter A fragments (latency hides under MFMA + epilogue)
        bf16x8 afn[8];
        if (i < 5) {
            const ushort* apn = sampled + (size_t)(base + 16 + ln) * 256 + quad * 8;
#pragma unroll
            for (int s = 0; s < 8; ++s) afn[s] = *(const bf16x8*)(apn + s * 32);
        }
        // this-iter residual src values
        float sv[4][4];
#pragma unroll
        for (int reg = 0; reg < 4; ++reg) {
            const float* sp = src + (size_t)(base + quad * 4 + reg) * 256 + wv * 64 + ln;
#pragma unroll
            for (int t = 0; t < 4; ++t) sv[reg][t] = sp[t * 16];
        }

        f32x4 acc[4] = {{0,0,0,0},{0,0,0,0},{0,0,0,0},{0,0,0,0}};
#pragma unroll
        for (int s = 0; s < 8; ++s)
#pragma unroll
            for (int t = 0; t < 4; ++t) {
                bf16x8 bf = *(const bf16x8*)(blds +
                              (size_t)(wv * 64 + t * 16 + ln) * 264 + s * 32 + quad * 8);
                acc[t] = __builtin_amdgcn_mfma_f32_16x16x32_bf16(af[s], bf, acc[t], 0, 0, 0);
            }

        // bias + residual + per-row partial sums (row = base + quad*4 + reg)
#pragma unroll
        for (int reg = 0; reg < 4; ++reg) {
            float s1 = 0.f, s2 = 0.f;
#pragma unroll
            for (int t = 0; t < 4; ++t) {
                float v = acc[t][reg] + bias[t] + sv[reg][t];
                acc[t][reg] = v;
                s1 += v; s2 += v * v;
            }
#pragma unroll
            for (int o = 8; o; o >>= 1) {
                s1 += __shfl_xor(s1, o, 16);
                s2 += __shfl_xor(s2, o, 16);
            }
            if (ln == 0) {
                sm[i & 1][wv][quad * 4 + reg][0] = s1;
                sm[i & 1][wv][quad * 4 + reg][1] = s2;
            }
        }
        __syncthreads();

#pragma unroll
        for (int reg = 0; reg < 4; ++reg) {
            const int r16 = quad * 4 + reg;
            float s1 = sm[i & 1][0][r16][0] + sm[i & 1][1][r16][0]
                     + sm[i & 1][2][r16][0] + sm[i & 1][3][r16][0];
            float s2 = sm[i & 1][0][r16][1] + sm[i & 1][1][r16][1]
                     + sm[i & 1][2][r16][1] + sm[i & 1][3][r16][1];
            float mu  = s1 * (1.f / 256.f);
            float var = s2 * (1.f / 256.f) - mu * mu;
            float rs  = rsqrtf(var + 1e-5f);
            const int row = base + quad * 4 + reg;
            float* op = out + (size_t)row * 256 + wv * 64 + ln;
#pragma unroll
            for (int t = 0; t < 4; ++t)
                op[t * 16] = (acc[t][reg] - mu) * rs * gam[t] + bet[t];
        }

        base += 16;
#pragma unroll
        for (int s = 0; s < 8; ++s) af[s] = afn[s];
    }
}

// ---------------------------------------------------------------------------
extern "C" void kernel_launch(void* const* d_in, const int* in_sizes, int n_in,
                              void* d_out, int out_size, void* d_ws, size_t ws_size,
                              hipStream_t stream)
{
    const float* src     = (const float*)d_in[0];
    const float* refp    = (const float*)d_in[1];
    const float* w_value = (const float*)d_in[4];
    const float* b_value = (const float*)d_in[5];
    const float* w_off   = (const float*)d_in[6];
    const float* b_off   = (const float*)d_in[7];
    const float* w_attn  = (const float*)d_in[8];
    const float* b_attn  = (const float*)d_in[9];
    const float* w_out   = (const float*)d_in[10];
    const float* b_out   = (const float*)d_in[11];
    const float* gamma   = (const float*)d_in[12];
    const float* beta    = (const float*)d_in[13];

    char* ws = (char*)d_ws;
    ushort*   val_t    = (ushort*)  (ws);                   // 12,533,760 B
    uint32_t* val_pair = (uint32_t*)(ws + 12533760);        // 25,067,520 B
    ushort*   src_bf   = (ushort*)  (ws + 12533760);        // alias of val_pair
                                                            // (src_bf dead before
                                                            //  pair_kernel writes)
    ushort*   off_f16  = (ushort*)  (ws + 37601280);        // 12,533,760 B
    ushort*   attn_f16 = (ushort*)  (ws + 50135040);        //  6,266,880 B
    uint32_t* sampled  = (uint32_t*)(ws + 62668800);        // 12,533,760 B (no alias)
    ushort*   B_pack   = (ushort*)  (ws + 75202560);        //    327,680 B
    ushort*   w_out_t  = (ushort*)  (ws + 75530240);        //    131,072 B
    float*    b_pack   = (float*)   (ws + 75661312);        //      2,560 B
    float*    out      = (float*)d_out;

    conv_kernel<<<7019, 256, 0, stream>>>(w_value, w_off, w_attn, b_value, b_off,
                                          b_attn, w_out, src, B_pack, w_out_t,
                                          b_pack, src_bf);
    proj_gemm<<<dim3(192, 5), 256, 0, stream>>>(src_bf, B_pack, b_pack, val_t,
                                                off_f16, attn_f16);
    pair_kernel<<<6120, 256, 0, stream>>>(val_t, val_pair);
    sample_kernel<<<12240, 256, 0, stream>>>(refp, val_pair, off_f16, attn_f16,
                                             sampled);
    out_ln_gemm<<<255, 256, 0, stream>>>((const ushort*)sampled, w_out_t,
                                         b_out, src, gamma, beta, out);
}